// Round 14
// baseline (560.499 us; speedup 1.0000x reference)
//
#include <hip/hip_runtime.h>
#include <cstdint>

using bf16x8 = __attribute__((ext_vector_type(8))) __bf16;
using f32x4  = __attribute__((ext_vector_type(4))) float;
using s16x8  = __attribute__((ext_vector_type(8))) short;
using s16x4  = __attribute__((ext_vector_type(4))) short;

#define DI static __device__ __forceinline__

#define SB __builtin_amdgcn_sched_barrier(0)
#define VMCNT(n) do { asm volatile("s_waitcnt vmcnt(" #n ")" ::: "memory"); SB; } while (0)
#define LGKM0    do { asm volatile("s_waitcnt lgkmcnt(0)" ::: "memory"); SB; } while (0)
#define BAR      do { SB; __builtin_amdgcn_s_barrier(); SB; } while (0)

DI short f2bf(float f) {
  unsigned u = __float_as_uint(f);
  u = (u + 0x7fffu + ((u >> 16) & 1u)) >> 16;
  return (short)u;
}
DI short f2bf_trunc(float f) { return (short)(__float_as_uint(f) >> 16); }
DI float bf2f(short s) {
  return __uint_as_float(((unsigned)(unsigned short)s) << 16);
}

DI void gload16(const short* g, short* l) {
  __builtin_amdgcn_global_load_lds((const __attribute__((address_space(1))) unsigned*)g,
                                   (__attribute__((address_space(3))) unsigned*)l, 16, 0, 0);
}

DI f32x4 mfma16(bf16x8 a, bf16x8 b, f32x4 c) {
  return __builtin_amdgcn_mfma_f32_16x16x32_bf16(a, b, c, 0, 0, 0);
}

// Stage a [256 rows x 32 k] bf16 panel (16 KB) into LDS, XOR-swizzled.
template<int CALLS>
DI void stageW(const short* __restrict__ W, int rs, int koff, short* dst, int w, int lane) {
  #pragma unroll
  for (int i = 0; i < CALLS; ++i) {
    int idx = (w * CALLS + i) * 64 + lane;
    int row = idx >> 2, slot = idx & 3;
    gload16(W + (size_t)row * rs + koff + (slot ^ ((row ^ (row >> 2)) & 3)) * 8,
            dst + (w * CALLS + i) * 512);
  }
}

// ---------------- merged weight prep (1 launch) ----------------
__global__ void k_prep(const float* __restrict__ qkvw, const float* __restrict__ qkvb,
                       const float* __restrict__ projw, const float* __restrict__ w1,
                       const float* __restrict__ w2,
                       short* __restrict__ WqkvT, float* __restrict__ qkvbp,
                       short* __restrict__ WprojT, short* __restrict__ W1T,
                       short* __restrict__ W2T) {
  int b = blockIdx.x, tid = threadIdx.x;
  if (b < 768) {
    int idx = b * 256 + tid;
    int jn = idx >> 8, k = idx & 255;
    int q = jn >> 8, rest = jn & 255, h = rest >> 5, d = rest & 31;
    int jo = h * 96 + d * 3 + q;
    WqkvT[idx] = f2bf(qkvw[(size_t)k * 768 + jo]);
    if (k == 0) qkvbp[jn] = qkvb[jo];
  } else if (b < 1024) {
    int idx = (b - 768) * 256 + tid;
    int n = idx >> 8, k = idx & 255;
    WprojT[idx] = f2bf(projw[(size_t)k * 256 + n]);
  } else if (b < 2048) {
    int idx = (b - 1024) * 256 + tid;
    int n = idx >> 8, k = idx & 255;
    W1T[idx] = f2bf(w1[(size_t)k * 1024 + n]);
  } else {
    int idx = (b - 2048) * 256 + tid;
    int n = idx >> 10, k = idx & 1023;
    W2T[idx] = f2bf(w2[(size_t)k * 256 + n]);
  }
}

// ---------------- fused LN1 + QKV + attention + proj + LN2: one block per window --------
// LDS: Qs 32K (LN1 As alias) | Ks 32K (-> AOs) | VT 36864 | Ws 2x16K | Ps 9216 = 144384.
__global__ __launch_bounds__(256, 2) void k_qav(
    const float* __restrict__ x, const float* __restrict__ g1, const float* __restrict__ b1v,
    const short* __restrict__ WqkvT, const float* __restrict__ qbp,
    const short* __restrict__ WprojT, const float* __restrict__ pb,
    short* __restrict__ y2, short* __restrict__ hresb,
    const float* __restrict__ g2, const float* __restrict__ b2,
    int win0, int chunk_off)
{
  extern __shared__ __align__(16) char dsm[];
  short* Qs = (short*)dsm;               // [64][256] swz; LN1 As alias
  short* Ks = (short*)(dsm + 32768);     // [64][256] swz; later AOs
  short* VT = (short*)(dsm + 65536);     // [256 ch][72 tok]
  short* Ws = (short*)(dsm + 102400);    // 2 x 8192 shorts
  short* Ps = (short*)(dsm + 135168);    // [64][72]; later redS/redQ
  const int tid = threadIdx.x, lane = tid & 63, w = tid >> 6;
  const int l15 = lane & 15, hi = lane >> 4, hi4 = hi * 4;
  const int wg = win0 + blockIdx.x;
  const int bm0 = blockIdx.x * 64;
  const int bb = wg >> 6, wl = wg & 63, wrr = wl >> 3, wcc = wl & 7;

  stageW<4>(WqkvT, 256, 0, &Ws[0], w, lane);        // qkv seq0
  // ---- LN1 + window gather -> Qs(As) swizzled ----
  #pragma unroll
  for (int p = 0; p < 4; ++p) {
    int tok = w * 16 + p * 4 + hi;
    int sr = bb * 4096 + ((tok >> 3) * 8 + wrr) * 64 + (tok & 7) * 8 + wcc;
    const float* xr = x + (size_t)sr * 256;
    float4 v[4];
    #pragma unroll
    for (int ii = 0; ii < 4; ++ii) v[ii] = *(const float4*)(xr + l15 * 4 + ii * 64);
    float s = 0.f, q = 0.f;
    #pragma unroll
    for (int ii = 0; ii < 4; ++ii) {
      s += v[ii].x + v[ii].y + v[ii].z + v[ii].w;
      q += v[ii].x * v[ii].x + v[ii].y * v[ii].y + v[ii].z * v[ii].z + v[ii].w * v[ii].w;
    }
    #pragma unroll
    for (int mk = 1; mk < 16; mk <<= 1) { s += __shfl_xor(s, mk); q += __shfl_xor(q, mk); }
    float mean = s * (1.f / 256.f);
    float var  = q * (1.f / 256.f) - mean * mean;
    float rstd = rsqrtf(var + 1e-5f);
    #pragma unroll
    for (int ii = 0; ii < 4; ++ii) {
      float4 gv = *(const float4*)(g1 + l15 * 4 + ii * 64);
      float4 bv = *(const float4*)(b1v + l15 * 4 + ii * 64);
      s16x4 o;
      o[0] = f2bf((v[ii].x - mean) * rstd * gv.x + bv.x);
      o[1] = f2bf((v[ii].y - mean) * rstd * gv.y + bv.y);
      o[2] = f2bf((v[ii].z - mean) * rstd * gv.z + bv.z);
      o[3] = f2bf((v[ii].w - mean) * rstd * gv.w + bv.w);
      int c8 = (l15 >> 1) + ii * 8;
      *(s16x4*)(Qs + tok * 256 + ((c8 ^ (tok & 7)) << 3) + (l15 & 1) * 4) = o;
    }
  }
  LGKM0;
  BAR;
  // hoist LN1 output to regs (reused for Q, K, V GEMMs)
  bf16x8 af[4][8];
  #pragma unroll
  for (int m = 0; m < 4; ++m) {
    int row = m * 16 + l15;
    #pragma unroll
    for (int s = 0; s < 8; ++s)
      af[m][s] = *(const bf16x8*)(Qs + row * 256 + (((s * 4 + hi) ^ (row & 7)) << 3));
  }
  // ---- QKV GEMM: 3 parts x 8 staged steps; outputs -> LDS ----
  int cur = 0;
  for (int p = 0; p < 3; ++p) {
    f32x4 acc[4][4] = {};
    for (int s = 0; s < 8; ++s) {
      int nseq = p * 8 + s + 1;
      if (nseq < 24) stageW<4>(WqkvT + (size_t)(nseq >> 3) * 65536, 256, (nseq & 7) * 32,
                               &Ws[(cur ^ 1) * 8192], w, lane);
      else           stageW<4>(WprojT, 256, 0, &Ws[(cur ^ 1) * 8192], w, lane);  // proj p0
      VMCNT(4);
      BAR;
      bf16x8 wf[4];
      #pragma unroll
      for (int n = 0; n < 4; ++n) {
        int rc = w * 64 + n * 16 + l15;
        wf[n] = *(const bf16x8*)(&Ws[cur * 8192] + rc * 32 + ((hi ^ ((rc ^ (rc >> 2)) & 3)) << 3));
      }
      __builtin_amdgcn_s_setprio(1);
      #pragma unroll
      for (int m = 0; m < 4; ++m)
        #pragma unroll
        for (int n = 0; n < 4; ++n) acc[m][n] = mfma16(wf[n], af[m][s], acc[m][n]);
      __builtin_amdgcn_s_setprio(0);
      LGKM0;
      BAR;
      cur ^= 1;
    }
    // epilogue -> LDS (acc[m][n][j] = out[row=m*16+l15][col=w*64+n*16+hi4+j])
    if (p < 2) {
      short* dstL = (p == 0) ? Qs : Ks;
      const float sc = (p == 0) ? 0.17677669529663687f : 1.0f;
      #pragma unroll
      for (int n = 0; n < 4; ++n) {
        int colg = w * 64 + n * 16 + hi4;
        float4 bbv = *(const float4*)(qbp + p * 256 + colg);
        int chunk = colg >> 3;
        #pragma unroll
        for (int m = 0; m < 4; ++m) {
          int row = m * 16 + l15;
          s16x4 o;
          o[0] = f2bf_trunc((acc[m][n][0] + bbv.x) * sc);
          o[1] = f2bf_trunc((acc[m][n][1] + bbv.y) * sc);
          o[2] = f2bf_trunc((acc[m][n][2] + bbv.z) * sc);
          o[3] = f2bf_trunc((acc[m][n][3] + bbv.w) * sc);
          *(s16x4*)(dstL + row * 256 + ((chunk ^ (row & 7)) << 3) + (hi4 & 7)) = o;
        }
      }
    } else {
      // V -> VT transposed scatter
      #pragma unroll
      for (int n = 0; n < 4; ++n) {
        int colg = w * 64 + n * 16 + hi4;
        float4 bbv = *(const float4*)(qbp + 512 + colg);
        float bj[4] = {bbv.x, bbv.y, bbv.z, bbv.w};
        #pragma unroll
        for (int m = 0; m < 4; ++m) {
          int tok = m * 16 + l15;
          #pragma unroll
          for (int j = 0; j < 4; ++j)
            VT[(colg + j) * 72 + tok] = f2bf_trunc(acc[m][n][j] + bj[j]);
        }
      }
    }
  }
  LGKM0;
  BAR;            // Qs/Ks/VT visible to all waves
  // ---- attention (wave owns rows w*16..+16, loops all 8 heads) ----
  bf16x8 aq[8];
  #pragma unroll
  for (int h = 0; h < 8; ++h) {
    int row = w * 16 + l15;
    aq[h] = *(const bf16x8*)(Qs + row * 256 + (((h * 4 + hi) ^ (row & 7)) << 3));
  }
  f32x4 zero = {0.f, 0.f, 0.f, 0.f};
  s16x4 ob[8][2];
  #pragma unroll
  for (int h = 0; h < 8; ++h) {
    bf16x8 bk[4];
    #pragma unroll
    for (int t = 0; t < 4; ++t) {
      int row = t * 16 + l15;
      bk[t] = *(const bf16x8*)(Ks + row * 256 + (((h * 4 + hi) ^ (row & 7)) << 3));
    }
    f32x4 s[4];
    #pragma unroll
    for (int t = 0; t < 4; ++t) s[t] = mfma16(aq[h], bk[t], zero);
    float rs[4];
    #pragma unroll
    for (int j = 0; j < 4; ++j) {
      float m = fmaxf(fmaxf(s[0][j], s[1][j]), fmaxf(s[2][j], s[3][j]));
      #pragma unroll
      for (int mk = 1; mk < 16; mk <<= 1) m = fmaxf(m, __shfl_xor(m, mk));
      float sum = 0.f;
      #pragma unroll
      for (int t = 0; t < 4; ++t) { float p = __expf(s[t][j] - m); s[t][j] = p; sum += p; }
      #pragma unroll
      for (int mk = 1; mk < 16; mk <<= 1) sum += __shfl_xor(sum, mk);
      rs[j] = 1.f / sum;
    }
    #pragma unroll
    for (int t = 0; t < 4; ++t)
      #pragma unroll
      for (int j = 0; j < 4; ++j)
        Ps[(w * 16 + hi4 + j) * 72 + t * 16 + l15] = f2bf_trunc(s[t][j] * rs[j]);
    LGKM0;        // same-wave Ps write -> read
    f32x4 o0 = zero, o1 = zero;
    #pragma unroll
    for (int ks = 0; ks < 2; ++ks) {
      bf16x8 ap  = *(const bf16x8*)&Ps[(w * 16 + l15) * 72 + ks * 32 + hi * 8];
      bf16x8 bv0 = *(const bf16x8*)&VT[(h * 32 + l15) * 72 + ks * 32 + hi * 8];
      bf16x8 bv1 = *(const bf16x8*)&VT[(h * 32 + 16 + l15) * 72 + ks * 32 + hi * 8];
      o0 = mfma16(bv0, ap, o0);
      o1 = mfma16(bv1, ap, o1);
    }
    #pragma unroll
    for (int j = 0; j < 4; ++j) { ob[h][0][j] = f2bf_trunc(o0[j]); ob[h][1][j] = f2bf_trunc(o1[j]); }
  }
  BAR;            // all waves done with Ks; safe to overwrite with AOs
  short* AOs = Ks;
  {
    int tok = w * 16 + l15;
    #pragma unroll
    for (int h = 0; h < 8; ++h)
      #pragma unroll
      for (int dt = 0; dt < 2; ++dt) {
        int ch = h * 32 + dt * 16 + hi4;
        int chunk = ch >> 3;
        *(s16x4*)(AOs + tok * 256 + ((chunk ^ (tok & 7)) << 3) + (hi4 & 7)) = ob[h][dt];
      }
  }
  LGKM0;
  BAR;            // AOs visible
  bf16x8 af2[4][8];
  #pragma unroll
  for (int m = 0; m < 4; ++m) {
    int row = m * 16 + l15;
    #pragma unroll
    for (int s = 0; s < 8; ++s)
      af2[m][s] = *(const bf16x8*)(AOs + row * 256 + (((s * 4 + hi) ^ (row & 7)) << 3));
  }
  // ---- proj GEMM (Wproj panel 0 already resident in Ws[cur]) ----
  f32x4 acc[4][4] = {};
  for (int s = 0; s < 8; ++s) {
    stageW<4>(WprojT, 256, ((s + 1) & 7) * 32, &Ws[(cur ^ 1) * 8192], w, lane);
    VMCNT(4);
    BAR;
    bf16x8 bfr[4];
    #pragma unroll
    for (int n = 0; n < 4; ++n) {
      int rc = w * 64 + n * 16 + l15;
      bfr[n] = *(const bf16x8*)(&Ws[cur * 8192] + rc * 32 + ((hi ^ ((rc ^ (rc >> 2)) & 3)) << 3));
    }
    __builtin_amdgcn_s_setprio(1);
    #pragma unroll
    for (int m = 0; m < 4; ++m)
      #pragma unroll
      for (int n = 0; n < 4; ++n) acc[m][n] = mfma16(af2[m][s], bfr[n], acc[m][n]);
    __builtin_amdgcn_s_setprio(0);
    LGKM0;
    BAR;
    cur ^= 1;
  }
  // ---- epilogue: + bias + x residual (window->spatial), LN2, write hres + y2 ----
  float* redS = (float*)Ps;
  float* redQ = redS + 256;
  int srow[4][4];
  #pragma unroll
  for (int m = 0; m < 4; ++m)
    #pragma unroll
    for (int j = 0; j < 4; ++j) {
      int wrow = chunk_off + bm0 + m * 16 + hi4 + j;
      int b2i = wrow >> 12, rem = wrow & 4095, wn2 = rem >> 6, tok = rem & 63;
      int rsp = (tok >> 3) * 8 + (wn2 >> 3);
      int csp = (tok & 7) * 8 + (wn2 & 7);
      srow[m][j] = b2i * 4096 + rsp * 64 + csp;
    }
  float s1[4][4] = {}, s2[4][4] = {};
  #pragma unroll
  for (int m = 0; m < 4; ++m)
    #pragma unroll
    for (int n = 0; n < 4; ++n) {
      int col = w * 64 + n * 16 + l15;
      float bia = pb[col];
      #pragma unroll
      for (int j = 0; j < 4; ++j) {
        float val = acc[m][n][j] + bia + x[(size_t)srow[m][j] * 256 + col];
        acc[m][n][j] = val;
        s1[m][j] += val; s2[m][j] += val * val;
      }
    }
  #pragma unroll
  for (int m = 0; m < 4; ++m)
    #pragma unroll
    for (int j = 0; j < 4; ++j) {
      float a = s1[m][j], bq = s2[m][j];
      #pragma unroll
      for (int mk = 1; mk < 16; mk <<= 1) { a += __shfl_xor(a, mk); bq += __shfl_xor(bq, mk); }
      s1[m][j] = a; s2[m][j] = bq;
    }
  if (l15 == 0) {
    #pragma unroll
    for (int m = 0; m < 4; ++m)
      #pragma unroll
      for (int j = 0; j < 4; ++j) {
        int rl = m * 16 + hi4 + j;
        redS[rl * 4 + w] = s1[m][j];
        redQ[rl * 4 + w] = s2[m][j];
      }
  }
  __syncthreads();
  #pragma unroll
  for (int m = 0; m < 4; ++m)
    #pragma unroll
    for (int j = 0; j < 4; ++j) {
      int rl = m * 16 + hi4 + j;
      float S = redS[rl * 4] + redS[rl * 4 + 1] + redS[rl * 4 + 2] + redS[rl * 4 + 3];
      float Qv = redQ[rl * 4] + redQ[rl * 4 + 1] + redQ[rl * 4 + 2] + redQ[rl * 4 + 3];
      float mean = S * (1.f / 256.f);
      float var  = Qv * (1.f / 256.f) - mean * mean;
      float rstd = rsqrtf(var + 1e-5f);
      int lrow = srow[m][j] - chunk_off;
      #pragma unroll
      for (int n = 0; n < 4; ++n) {
        int col = w * 64 + n * 16 + l15;
        float val = acc[m][n][j];
        hresb[(size_t)lrow * 256 + col] = f2bf(val);
        y2[(size_t)lrow * 256 + col] = f2bf((val - mean) * rstd * g2[col] + b2[col]);
      }
    }
}

// ---------------- fused MLP v11 (R12-exact) ----------------
__global__ __launch_bounds__(256, 2) void k_mlp(
    const short* __restrict__ y2, const short* __restrict__ hres,
    const short* __restrict__ W1T, const float* __restrict__ b1,
    const short* __restrict__ W2T, const float* __restrict__ b2,
    float* __restrict__ outp)
{
  extern __shared__ __align__(16) char dsm[];
  short* hs    = (short*)dsm;
  float* biasF = (float*)(dsm + 16384);
  short* Wb    = (short*)(dsm + 21504);
  const int tid = threadIdx.x, lane = tid & 63, w = tid >> 6;
  const int l15 = lane & 15, hi = lane >> 4, hi4 = hi * 4;
  const int wm = w >> 1, wn = w & 1;
  const int bm0 = blockIdx.x * 64;

  auto stage_seq = [&](int seq, int buf) {
    short* dst = Wb + buf * 8192;
    int hc = (seq >> 3) & 7, t = seq & 7;
    if (t < 4) {
      #pragma unroll
      for (int i = 0; i < 4; ++i) {
        int idx = (w * 4 + i) * 64 + lane;
        int row = idx >> 3, slot = idx & 7;
        gload16(W1T + (size_t)(hc * 128 + row) * 256 + t * 64 + (slot ^ (row & 7)) * 8,
                dst + (w * 4 + i) * 512);
      }
    } else {
      #pragma unroll
      for (int i = 0; i < 4; ++i) {
        int idx = (w * 4 + i) * 64 + lane;
        int row = idx >> 2, slot = idx & 3;
        gload16(W2T + (size_t)row * 1024 + hc * 128 + (t - 4) * 32 +
                    (slot ^ ((row ^ (row >> 2)) & 3)) * 8,
                dst + (w * 4 + i) * 512);
      }
    }
  };

  gload16((const short*)b1 + w * 512 + lane * 8, (short*)biasF + w * 512);
  if (w == 0) gload16((const short*)b2 + lane * 8, (short*)biasF + 2048);
  stage_seq(0, 0);
  bf16x8 af[2][8];
  #pragma unroll
  for (int m = 0; m < 2; ++m) {
    const short* yr = y2 + (size_t)(bm0 + wm * 32 + m * 16 + l15) * 256 + hi * 8;
    #pragma unroll
    for (int kk = 0; kk < 8; ++kk)
      af[m][kk] = *(const bf16x8*)(yr + kk * 32);
  }
  f32x4 oacc[2][8] = {};
  int cur = 0;
  for (int hc = 0; hc < 8; ++hc) {
    f32x4 acc1[2][4] = {};
    #pragma unroll
    for (int s = 0; s < 4; ++s) {
      stage_seq((hc * 8 + s + 1) & 63, cur ^ 1);
      VMCNT(4);
      BAR;
      const short* Wc = Wb + cur * 8192;
      #pragma unroll
      for (int q = 0; q < 2; ++q) {
        int kk = s * 2 + q;
        bf16x8 wf[4];
        #pragma unroll
        for (int n2 = 0; n2 < 4; ++n2) {
          int rc = wn * 64 + n2 * 16 + l15;
          wf[n2] = *(const bf16x8*)(Wc + rc * 64 + (((q * 4 + hi) ^ (rc & 7)) << 3));
        }
        __builtin_amdgcn_s_setprio(1);
        #pragma unroll
        for (int m = 0; m < 2; ++m)
          #pragma unroll
          for (int n2 = 0; n2 < 4; ++n2)
            acc1[m][n2] = mfma16(wf[n2], af[m][kk], acc1[m][n2]);
        __builtin_amdgcn_s_setprio(0);
      }
      LGKM0;
      BAR;
      cur ^= 1;
    }
    #pragma unroll
    for (int m = 0; m < 2; ++m)
      #pragma unroll
      for (int n2 = 0; n2 < 4; ++n2) {
        int xrow = wm * 32 + m * 16 + l15;
        int hcolb = wn * 64 + n2 * 16 + hi4;
        float4 bbv = *(const float4*)(biasF + hc * 128 + hcolb);
        float bj[4] = {bbv.x, bbv.y, bbv.z, bbv.w};
        s16x4 o;
        #pragma unroll
        for (int j = 0; j < 4; ++j) {
          float vv = acc1[m][n2][j] + bj[j];
          float z = vv + 0.044715f * vv * vv * vv;
          float e = __builtin_amdgcn_exp2f(z * -2.3022078900938913f);
          o[j] = f2bf_trunc(vv * __builtin_amdgcn_rcpf(1.f + e));
        }
        int chunk = hcolb >> 3;
        *(s16x4*)(hs + xrow * 128 + ((chunk ^ (xrow & 15)) << 3) + (hi & 1) * 4) = o;
      }
    LGKM0;
    BAR;
    #pragma unroll
    for (int s = 0; s < 4; ++s) {
      stage_seq((hc * 8 + 4 + s + 1) & 63, cur ^ 1);
      VMCNT(4);
      BAR;
      const short* Wc = Wb + cur * 8192;
      bf16x8 hf[2], w2f[8];
      #pragma unroll
      for (int m = 0; m < 2; ++m) {
        int xr = wm * 32 + m * 16 + l15;
        hf[m] = *(const bf16x8*)(hs + xr * 128 + (((s * 4 + hi) ^ (xr & 15)) << 3));
      }
      #pragma unroll
      for (int n = 0; n < 8; ++n) {
        int rc = wn * 128 + n * 16 + l15;
        w2f[n] = *(const bf16x8*)(Wc + rc * 32 + ((hi ^ ((rc ^ (rc >> 2)) & 3)) << 3));
      }
      __builtin_amdgcn_s_setprio(1);
      #pragma unroll
      for (int m = 0; m < 2; ++m)
        #pragma unroll
        for (int n = 0; n < 8; ++n)
          oacc[m][n] = mfma16(w2f[n], hf[m], oacc[m][n]);
      __builtin_amdgcn_s_setprio(0);
      LGKM0;
      BAR;
      cur ^= 1;
    }
  }
  #pragma unroll
  for (int m = 0; m < 2; ++m)
    #pragma unroll
    for (int n = 0; n < 8; ++n) {
      size_t row = (size_t)bm0 + wm * 32 + m * 16 + l15;
      int colb = wn * 128 + n * 16 + hi4;
      float4 bbv = *(const float4*)(biasF + 1024 + colb);
      s16x4 hr = *(const s16x4*)(hres + row * 256 + colb);
      float4 ov;
      ov.x = oacc[m][n][0] + bbv.x + bf2f(hr[0]);
      ov.y = oacc[m][n][1] + bbv.y + bf2f(hr[1]);
      ov.z = oacc[m][n][2] + bbv.z + bf2f(hr[2]);
      ov.w = oacc[m][n][3] + bbv.w + bf2f(hr[3]);
      *(float4*)(outp + row * 256 + colb) = ov;
    }
}

// ---------------- host ----------------
extern "C" void kernel_launch(void* const* d_in, const int* in_sizes, int n_in,
                              void* d_out, int out_size, void* d_ws, size_t ws_size,
                              hipStream_t stream) {
  const float* x     = (const float*)d_in[0];
  const float* ln1g  = (const float*)d_in[1];
  const float* ln1b  = (const float*)d_in[2];
  const float* qkvw  = (const float*)d_in[3];
  const float* qkvb  = (const float*)d_in[4];
  const float* projw = (const float*)d_in[5];
  const float* projb = (const float*)d_in[6];
  const float* ln2g  = (const float*)d_in[7];
  const float* ln2b  = (const float*)d_in[8];
  const float* w1    = (const float*)d_in[9];
  const float* b1    = (const float*)d_in[10];
  const float* w2    = (const float*)d_in[11];
  const float* b2    = (const float*)d_in[12];
  float* out = (float*)d_out;
  char* ws = (char*)d_ws;

  static int attr_set = 0;
  if (!attr_set) {
    hipFuncSetAttribute((const void*)k_mlp,
                        hipFuncAttributeMaxDynamicSharedMemorySize, 54272);
    hipFuncSetAttribute((const void*)k_qav,
                        hipFuncAttributeMaxDynamicSharedMemorySize, 144384);
    attr_set = 1;
  }

  const size_t MTOT = 131072;
  int nchunk;
  if (ws_size >= 2ull * MTOT * 512 + (2u << 20)) nchunk = 1;
  else if (ws_size >= 2ull * (MTOT / 2) * 512 + (2u << 20)) nchunk = 2;
  else nchunk = 4;
  const size_t M = MTOT / nchunk;
  const int nwin = (int)(M / 64);

  short* y2b  = (short*)ws;                          // M*256 shorts
  short* hrb  = y2b + M * 256;                       // M*256 shorts
  char*  wreg = ws + 2ull * M * 512;
  short* WqkvT  = (short*)wreg;                      // 393,216 B
  short* WprojT = (short*)(wreg + 393216);           // 131,072 B
  short* W1T    = (short*)(wreg + 524288);           // 524,288 B
  short* W2T    = (short*)(wreg + 1048576);          // 524,288 B
  float* qkvbp  = (float*)(wreg + 1572864);          // 3,072 B

  k_prep<<<3072, 256, 0, stream>>>(qkvw, qkvb, projw, w1, w2,
                                   WqkvT, qkvbp, WprojT, W1T, W2T);

  for (int c = 0; c < nchunk; ++c) {
    k_qav<<<nwin, 256, 144384, stream>>>(x, ln1g, ln1b, WqkvT, qkvbp,
                                         WprojT, projb, y2b, hrb, ln2g, ln2b,
                                         c * nwin, (int)(c * M));
    k_mlp<<<nwin, 256, 54272, stream>>>(y2b, hrb, W1T, b1, W2T, b2,
                                        out + (size_t)c * M * 256);
  }
}

// Round 15
// 523.663 us; speedup vs baseline: 1.0703x; 1.0703x over previous
//
#include <hip/hip_runtime.h>
#include <cstdint>

using bf16x8 = __attribute__((ext_vector_type(8))) __bf16;
using f32x4  = __attribute__((ext_vector_type(4))) float;
using s16x8  = __attribute__((ext_vector_type(8))) short;
using s16x4  = __attribute__((ext_vector_type(4))) short;

#define DI static __device__ __forceinline__

#define SB __builtin_amdgcn_sched_barrier(0)
#define VMCNT(n) do { asm volatile("s_waitcnt vmcnt(" #n ")" ::: "memory"); SB; } while (0)
#define LGKM0    do { asm volatile("s_waitcnt lgkmcnt(0)" ::: "memory"); SB; } while (0)
#define BAR      do { SB; __builtin_amdgcn_s_barrier(); SB; } while (0)

DI short f2bf(float f) {
  unsigned u = __float_as_uint(f);
  u = (u + 0x7fffu + ((u >> 16) & 1u)) >> 16;
  return (short)u;
}
DI short f2bf_trunc(float f) { return (short)(__float_as_uint(f) >> 16); }
DI float bf2f(short s) {
  return __uint_as_float(((unsigned)(unsigned short)s) << 16);
}

DI void gload16(const short* g, short* l) {
  __builtin_amdgcn_global_load_lds((const __attribute__((address_space(1))) unsigned*)g,
                                   (__attribute__((address_space(3))) unsigned*)l, 16, 0, 0);
}

DI f32x4 mfma16(bf16x8 a, bf16x8 b, f32x4 c) {
  return __builtin_amdgcn_mfma_f32_16x16x32_bf16(a, b, c, 0, 0, 0);
}

// Stage a [256 rows x 32 k] bf16 panel (16 KB) into LDS, XOR-swizzled.
template<int CALLS>
DI void stageW(const short* __restrict__ W, int rs, int koff, short* dst, int w, int lane) {
  #pragma unroll
  for (int i = 0; i < CALLS; ++i) {
    int idx = (w * CALLS + i) * 64 + lane;
    int row = idx >> 2, slot = idx & 3;
    gload16(W + (size_t)row * rs + koff + (slot ^ ((row ^ (row >> 2)) & 3)) * 8,
            dst + (w * CALLS + i) * 512);
  }
}

// ---------------- merged weight prep (1 launch) ----------------
__global__ void k_prep(const float* __restrict__ qkvw, const float* __restrict__ qkvb,
                       const float* __restrict__ projw, const float* __restrict__ w1,
                       const float* __restrict__ w2,
                       short* __restrict__ WqkvT, float* __restrict__ qkvbp,
                       short* __restrict__ WprojT, short* __restrict__ W1T,
                       short* __restrict__ W2T) {
  int b = blockIdx.x, tid = threadIdx.x;
  if (b < 768) {
    int idx = b * 256 + tid;
    int jn = idx >> 8, k = idx & 255;
    int q = jn >> 8, rest = jn & 255, h = rest >> 5, d = rest & 31;
    int jo = h * 96 + d * 3 + q;
    WqkvT[idx] = f2bf(qkvw[(size_t)k * 768 + jo]);
    if (k == 0) qkvbp[jn] = qkvb[jo];
  } else if (b < 1024) {
    int idx = (b - 768) * 256 + tid;
    int n = idx >> 8, k = idx & 255;
    WprojT[idx] = f2bf(projw[(size_t)k * 256 + n]);
  } else if (b < 2048) {
    int idx = (b - 1024) * 256 + tid;
    int n = idx >> 8, k = idx & 255;
    W1T[idx] = f2bf(w1[(size_t)k * 1024 + n]);
  } else {
    int idx = (b - 2048) * 256 + tid;
    int n = idx >> 10, k = idx & 1023;
    W2T[idx] = f2bf(w2[(size_t)k * 256 + n]);
  }
}

// ---------------- QKV: fused LN1 + window gather + staged-weight GEMM ----------------
__global__ __launch_bounds__(256, 2) void k_qkvln(
    const float* __restrict__ x, const float* __restrict__ g1, const float* __restrict__ b1v,
    const short* __restrict__ WqkvT, const float* __restrict__ qbp,
    short* __restrict__ qkv, int win0, int mtot)
{
  __shared__ __align__(16) short As[64 * 256];      // 32 KB
  __shared__ __align__(16) short Ws[2][256 * 32];   // 2 x 16 KB
  const int tid = threadIdx.x, lane = tid & 63, w = tid >> 6;
  const int l15 = lane & 15, hi = lane >> 4, hi4 = hi * 4;
  const int wg = win0 + blockIdx.x;
  const int bb = wg >> 6, wl = wg & 63, wrr = wl >> 3, wcc = wl & 7;
  stageW<4>(WqkvT, 256, 0, &Ws[0][0], w, lane);     // seq0
  #pragma unroll
  for (int p = 0; p < 4; ++p) {
    int tok = w * 16 + p * 4 + hi;
    int sr = bb * 4096 + ((tok >> 3) * 8 + wrr) * 64 + (tok & 7) * 8 + wcc;
    const float* xr = x + (size_t)sr * 256;
    float4 v[4];
    #pragma unroll
    for (int ii = 0; ii < 4; ++ii) v[ii] = *(const float4*)(xr + l15 * 4 + ii * 64);
    float s = 0.f, q = 0.f;
    #pragma unroll
    for (int ii = 0; ii < 4; ++ii) {
      s += v[ii].x + v[ii].y + v[ii].z + v[ii].w;
      q += v[ii].x * v[ii].x + v[ii].y * v[ii].y + v[ii].z * v[ii].z + v[ii].w * v[ii].w;
    }
    #pragma unroll
    for (int mk = 1; mk < 16; mk <<= 1) { s += __shfl_xor(s, mk); q += __shfl_xor(q, mk); }
    float mean = s * (1.f / 256.f);
    float var  = q * (1.f / 256.f) - mean * mean;
    float rstd = rsqrtf(var + 1e-5f);
    #pragma unroll
    for (int ii = 0; ii < 4; ++ii) {
      float4 gv = *(const float4*)(g1 + l15 * 4 + ii * 64);
      float4 bv = *(const float4*)(b1v + l15 * 4 + ii * 64);
      s16x4 o;
      o[0] = f2bf((v[ii].x - mean) * rstd * gv.x + bv.x);
      o[1] = f2bf((v[ii].y - mean) * rstd * gv.y + bv.y);
      o[2] = f2bf((v[ii].z - mean) * rstd * gv.z + bv.z);
      o[3] = f2bf((v[ii].w - mean) * rstd * gv.w + bv.w);
      int c8 = (l15 >> 1) + ii * 8;
      *(s16x4*)(As + tok * 256 + ((c8 ^ (tok & 7)) << 3) + (l15 & 1) * 4) = o;
    }
  }
  LGKM0;
  BAR;
  bf16x8 af[4][8];
  #pragma unroll
  for (int m = 0; m < 4; ++m) {
    int row = m * 16 + l15;
    #pragma unroll
    for (int s = 0; s < 8; ++s)
      af[m][s] = *(const bf16x8*)(As + row * 256 + (((s * 4 + hi) ^ (row & 7)) << 3));
  }
  int cur = 0;
  for (int p = 0; p < 3; ++p) {
    f32x4 acc[4][4] = {};
    for (int s = 0; s < 8; ++s) {
      int nseq = p * 8 + s + 1; if (nseq >= 24) nseq = 0;
      stageW<4>(WqkvT + (size_t)(nseq >> 3) * 65536, 256, (nseq & 7) * 32,
                &Ws[cur ^ 1][0], w, lane);
      VMCNT(4);
      BAR;
      bf16x8 wf[4];
      #pragma unroll
      for (int n = 0; n < 4; ++n) {
        int rc = w * 64 + n * 16 + l15;
        wf[n] = *(const bf16x8*)(&Ws[cur][0] + rc * 32 + ((hi ^ ((rc ^ (rc >> 2)) & 3)) << 3));
      }
      __builtin_amdgcn_s_setprio(1);
      #pragma unroll
      for (int m = 0; m < 4; ++m)
        #pragma unroll
        for (int n = 0; n < 4; ++n) acc[m][n] = mfma16(wf[n], af[m][s], acc[m][n]);
      __builtin_amdgcn_s_setprio(0);
      LGKM0;
      BAR;
      cur ^= 1;
    }
    const float sc = (p == 0) ? 0.17677669529663687f : 1.0f;
    short* dst = qkv + ((size_t)p * mtot + (size_t)blockIdx.x * 64) * 256;
    #pragma unroll
    for (int n = 0; n < 4; ++n) {
      int colg = w * 64 + n * 16 + hi4;
      float4 bbv = *(const float4*)(qbp + p * 256 + colg);
      #pragma unroll
      for (int m = 0; m < 4; ++m) {
        int row = m * 16 + l15;
        s16x4 o;
        o[0] = f2bf_trunc((acc[m][n][0] + bbv.x) * sc);
        o[1] = f2bf_trunc((acc[m][n][1] + bbv.y) * sc);
        o[2] = f2bf_trunc((acc[m][n][2] + bbv.z) * sc);
        o[3] = f2bf_trunc((acc[m][n][3] + bbv.w) * sc);
        *(s16x4*)(dst + (size_t)row * 256 + colg) = o;
      }
    }
  }
}

// ---------------- fused attention + proj + residual + LN2 ----------------
// One block per window. LDS: VT[256][72] 36864 (->AOs 32K) | Ws 2x16K | Ps[64][72] 9216.
__global__ __launch_bounds__(256, 2) void k_attnproj(
    const short* __restrict__ qkv, const short* __restrict__ WprojT,
    const float* __restrict__ pb, const float* __restrict__ x,
    short* __restrict__ y2, short* __restrict__ hresb,
    const float* __restrict__ g2, const float* __restrict__ b2,
    int chunk_off, int mtot)
{
  extern __shared__ __align__(16) char dsm[];
  short* VT = (short*)dsm;               // [256 ch][72 tok]; later AOs [64][256] swizzled
  short* Ws = (short*)(dsm + 36864);     // 2 x 8192 shorts
  short* Ps = (short*)(dsm + 69632);     // [64][72]; later redS/redQ
  const int tid = threadIdx.x, lane = tid & 63, w = tid >> 6;
  const int l15 = lane & 15, hi = lane >> 4, hi4 = hi * 4;
  const int win = blockIdx.x, bm0 = win * 64;
  const size_t qbase = (size_t)win * 64 * 256;
  const short* Qg = qkv;
  const short* Kg = qkv + (size_t)mtot * 256;
  const short* Vg = qkv + 2 * (size_t)mtot * 256;

  stageW<4>(WprojT, 256, 0, &Ws[0], w, lane);   // proj panel 0 (lands during attention)

  // V -> VT transpose staging (coalesced global reads, scatter b16 LDS writes)
  {
    int tok = tid >> 2, c4 = (tid & 3) * 8;
    #pragma unroll
    for (int c8 = 0; c8 < 8; ++c8) {
      s16x8 vv = *(const s16x8*)(Vg + qbase + (size_t)tok * 256 + c4 + c8 * 32);
      #pragma unroll
      for (int e = 0; e < 8; ++e) VT[(c4 + c8 * 32 + e) * 72 + tok] = vv[e];
    }
  }
  // Q fragments for this wave's 16 rows, all 8 heads
  bf16x8 aq[8];
  #pragma unroll
  for (int h = 0; h < 8; ++h)
    aq[h] = *(const bf16x8*)(Qg + qbase + (size_t)(w * 16 + l15) * 256 + h * 32 + hi * 8);
  LGKM0;
  BAR;            // VT visible to all waves

  f32x4 zero = {0.f, 0.f, 0.f, 0.f};
  s16x4 ob[8][2];
  #pragma unroll
  for (int h = 0; h < 8; ++h) {
    bf16x8 bk[4];
    #pragma unroll
    for (int t = 0; t < 4; ++t)
      bk[t] = *(const bf16x8*)(Kg + qbase + (size_t)(t * 16 + l15) * 256 + h * 32 + hi * 8);
    f32x4 s[4];
    #pragma unroll
    for (int t = 0; t < 4; ++t) s[t] = mfma16(aq[h], bk[t], zero);
    // softmax over k (rows q = w*16 + hi4 + j, k = t*16 + l15)
    float rs[4];
    #pragma unroll
    for (int j = 0; j < 4; ++j) {
      float m = fmaxf(fmaxf(s[0][j], s[1][j]), fmaxf(s[2][j], s[3][j]));
      #pragma unroll
      for (int mk = 1; mk < 16; mk <<= 1) m = fmaxf(m, __shfl_xor(m, mk));
      float sum = 0.f;
      #pragma unroll
      for (int t = 0; t < 4; ++t) { float p = __expf(s[t][j] - m); s[t][j] = p; sum += p; }
      #pragma unroll
      for (int mk = 1; mk < 16; mk <<= 1) sum += __shfl_xor(sum, mk);
      rs[j] = 1.f / sum;
    }
    #pragma unroll
    for (int t = 0; t < 4; ++t)
      #pragma unroll
      for (int j = 0; j < 4; ++j)
        Ps[(w * 16 + hi4 + j) * 72 + t * 16 + l15] = f2bf_trunc(s[t][j] * rs[j]);
    LGKM0;        // same-wave Ps write -> read
    f32x4 o0 = zero, o1 = zero;
    #pragma unroll
    for (int ks = 0; ks < 2; ++ks) {
      bf16x8 ap  = *(const bf16x8*)&Ps[(w * 16 + l15) * 72 + ks * 32 + hi * 8];
      bf16x8 bv0 = *(const bf16x8*)&VT[(h * 32 + l15) * 72 + ks * 32 + hi * 8];
      bf16x8 bv1 = *(const bf16x8*)&VT[(h * 32 + 16 + l15) * 72 + ks * 32 + hi * 8];
      o0 = mfma16(bv0, ap, o0);   // lane -> O[tok=w*16+l15][ch=h*32+hi4+j]
      o1 = mfma16(bv1, ap, o1);   // lane -> O[tok][ch=h*32+16+hi4+j]
    }
    #pragma unroll
    for (int j = 0; j < 4; ++j) { ob[h][0][j] = f2bf_trunc(o0[j]); ob[h][1][j] = f2bf_trunc(o1[j]); }
  }
  BAR;            // all waves done reading VT; safe to overwrite with AOs
  short* AOs = VT;
  {
    int tok = w * 16 + l15;
    #pragma unroll
    for (int h = 0; h < 8; ++h)
      #pragma unroll
      for (int dt = 0; dt < 2; ++dt) {
        int ch = h * 32 + dt * 16 + hi4;
        int chunk = ch >> 3;
        *(s16x4*)(AOs + tok * 256 + ((chunk ^ (tok & 7)) << 3) + (hi4 & 7)) = ob[h][dt];
      }
  }
  LGKM0;
  BAR;            // AOs visible
  // A fragments for proj
  bf16x8 af[4][8];
  #pragma unroll
  for (int m = 0; m < 4; ++m) {
    int row = m * 16 + l15;
    #pragma unroll
    for (int s = 0; s < 8; ++s)
      af[m][s] = *(const bf16x8*)(AOs + row * 256 + (((s * 4 + hi) ^ (row & 7)) << 3));
  }
  // proj GEMM: staged Wproj panels (panel 0 already resident)
  int cur = 0;
  f32x4 acc[4][4] = {};
  for (int s = 0; s < 8; ++s) {
    stageW<4>(WprojT, 256, ((s + 1) & 7) * 32, Ws + (cur ^ 1) * 8192, w, lane);
    VMCNT(4);
    BAR;
    bf16x8 bfr[4];
    #pragma unroll
    for (int n = 0; n < 4; ++n) {
      int rc = w * 64 + n * 16 + l15;
      bfr[n] = *(const bf16x8*)(Ws + cur * 8192 + rc * 32 + ((hi ^ ((rc ^ (rc >> 2)) & 3)) << 3));
    }
    __builtin_amdgcn_s_setprio(1);
    #pragma unroll
    for (int m = 0; m < 4; ++m)
      #pragma unroll
      for (int n = 0; n < 4; ++n) acc[m][n] = mfma16(af[m][s], bfr[n], acc[m][n]);
    __builtin_amdgcn_s_setprio(0);
    LGKM0;
    BAR;
    cur ^= 1;
  }
  // epilogue: + bias + x residual (window->spatial), LN2, write hres + y2
  float* redS = (float*)Ps;
  float* redQ = redS + 256;
  int srow[4][4];
  #pragma unroll
  for (int m = 0; m < 4; ++m)
    #pragma unroll
    for (int j = 0; j < 4; ++j) {
      int wrow = chunk_off + bm0 + m * 16 + hi4 + j;
      int bb = wrow >> 12, rem = wrow & 4095, wn2 = rem >> 6, tok = rem & 63;
      int rsp = (tok >> 3) * 8 + (wn2 >> 3);
      int csp = (tok & 7) * 8 + (wn2 & 7);
      srow[m][j] = bb * 4096 + rsp * 64 + csp;
    }
  float s1[4][4] = {}, s2[4][4] = {};
  #pragma unroll
  for (int m = 0; m < 4; ++m)
    #pragma unroll
    for (int n = 0; n < 4; ++n) {
      int col = w * 64 + n * 16 + l15;
      float bia = pb[col];
      #pragma unroll
      for (int j = 0; j < 4; ++j) {
        float val = acc[m][n][j] + bia + x[(size_t)srow[m][j] * 256 + col];
        acc[m][n][j] = val;
        s1[m][j] += val; s2[m][j] += val * val;
      }
    }
  #pragma unroll
  for (int m = 0; m < 4; ++m)
    #pragma unroll
    for (int j = 0; j < 4; ++j) {
      float a = s1[m][j], bq = s2[m][j];
      #pragma unroll
      for (int mk = 1; mk < 16; mk <<= 1) { a += __shfl_xor(a, mk); bq += __shfl_xor(bq, mk); }
      s1[m][j] = a; s2[m][j] = bq;
    }
  if (l15 == 0) {
    #pragma unroll
    for (int m = 0; m < 4; ++m)
      #pragma unroll
      for (int j = 0; j < 4; ++j) {
        int rl = m * 16 + hi4 + j;
        redS[rl * 4 + w] = s1[m][j];
        redQ[rl * 4 + w] = s2[m][j];
      }
  }
  __syncthreads();
  #pragma unroll
  for (int m = 0; m < 4; ++m)
    #pragma unroll
    for (int j = 0; j < 4; ++j) {
      int rl = m * 16 + hi4 + j;
      float S = redS[rl * 4] + redS[rl * 4 + 1] + redS[rl * 4 + 2] + redS[rl * 4 + 3];
      float Qs = redQ[rl * 4] + redQ[rl * 4 + 1] + redQ[rl * 4 + 2] + redQ[rl * 4 + 3];
      float mean = S * (1.f / 256.f);
      float var  = Qs * (1.f / 256.f) - mean * mean;
      float rstd = rsqrtf(var + 1e-5f);
      int lrow = srow[m][j] - chunk_off;
      #pragma unroll
      for (int n = 0; n < 4; ++n) {
        int col = w * 64 + n * 16 + l15;
        float val = acc[m][n][j];
        hresb[(size_t)lrow * 256 + col] = f2bf(val);
        y2[(size_t)lrow * 256 + col] = f2bf((val - mean) * rstd * g2[col] + b2[col]);
      }
    }
}

// ---------------- fused MLP v11 (R12-exact) ----------------
__global__ __launch_bounds__(256, 2) void k_mlp(
    const short* __restrict__ y2, const short* __restrict__ hres,
    const short* __restrict__ W1T, const float* __restrict__ b1,
    const short* __restrict__ W2T, const float* __restrict__ b2,
    float* __restrict__ outp)
{
  extern __shared__ __align__(16) char dsm[];
  short* hs    = (short*)dsm;
  float* biasF = (float*)(dsm + 16384);
  short* Wb    = (short*)(dsm + 21504);
  const int tid = threadIdx.x, lane = tid & 63, w = tid >> 6;
  const int l15 = lane & 15, hi = lane >> 4, hi4 = hi * 4;
  const int wm = w >> 1, wn = w & 1;
  const int bm0 = blockIdx.x * 64;

  auto stage_seq = [&](int seq, int buf) {
    short* dst = Wb + buf * 8192;
    int hc = (seq >> 3) & 7, t = seq & 7;
    if (t < 4) {
      #pragma unroll
      for (int i = 0; i < 4; ++i) {
        int idx = (w * 4 + i) * 64 + lane;
        int row = idx >> 3, slot = idx & 7;
        gload16(W1T + (size_t)(hc * 128 + row) * 256 + t * 64 + (slot ^ (row & 7)) * 8,
                dst + (w * 4 + i) * 512);
      }
    } else {
      #pragma unroll
      for (int i = 0; i < 4; ++i) {
        int idx = (w * 4 + i) * 64 + lane;
        int row = idx >> 2, slot = idx & 3;
        gload16(W2T + (size_t)row * 1024 + hc * 128 + (t - 4) * 32 +
                    (slot ^ ((row ^ (row >> 2)) & 3)) * 8,
                dst + (w * 4 + i) * 512);
      }
    }
  };

  gload16((const short*)b1 + w * 512 + lane * 8, (short*)biasF + w * 512);
  if (w == 0) gload16((const short*)b2 + lane * 8, (short*)biasF + 2048);
  stage_seq(0, 0);
  bf16x8 af[2][8];
  #pragma unroll
  for (int m = 0; m < 2; ++m) {
    const short* yr = y2 + (size_t)(bm0 + wm * 32 + m * 16 + l15) * 256 + hi * 8;
    #pragma unroll
    for (int kk = 0; kk < 8; ++kk)
      af[m][kk] = *(const bf16x8*)(yr + kk * 32);
  }
  f32x4 oacc[2][8] = {};
  int cur = 0;
  for (int hc = 0; hc < 8; ++hc) {
    f32x4 acc1[2][4] = {};
    #pragma unroll
    for (int s = 0; s < 4; ++s) {
      stage_seq((hc * 8 + s + 1) & 63, cur ^ 1);
      VMCNT(4);
      BAR;
      const short* Wc = Wb + cur * 8192;
      #pragma unroll
      for (int q = 0; q < 2; ++q) {
        int kk = s * 2 + q;
        bf16x8 wf[4];
        #pragma unroll
        for (int n2 = 0; n2 < 4; ++n2) {
          int rc = wn * 64 + n2 * 16 + l15;
          wf[n2] = *(const bf16x8*)(Wc + rc * 64 + (((q * 4 + hi) ^ (rc & 7)) << 3));
        }
        __builtin_amdgcn_s_setprio(1);
        #pragma unroll
        for (int m = 0; m < 2; ++m)
          #pragma unroll
          for (int n2 = 0; n2 < 4; ++n2)
            acc1[m][n2] = mfma16(wf[n2], af[m][kk], acc1[m][n2]);
        __builtin_amdgcn_s_setprio(0);
      }
      LGKM0;
      BAR;
      cur ^= 1;
    }
    #pragma unroll
    for (int m = 0; m < 2; ++m)
      #pragma unroll
      for (int n2 = 0; n2 < 4; ++n2) {
        int xrow = wm * 32 + m * 16 + l15;
        int hcolb = wn * 64 + n2 * 16 + hi4;
        float4 bbv = *(const float4*)(biasF + hc * 128 + hcolb);
        float bj[4] = {bbv.x, bbv.y, bbv.z, bbv.w};
        s16x4 o;
        #pragma unroll
        for (int j = 0; j < 4; ++j) {
          float vv = acc1[m][n2][j] + bj[j];
          float z = vv + 0.044715f * vv * vv * vv;
          float e = __builtin_amdgcn_exp2f(z * -2.3022078900938913f);
          o[j] = f2bf_trunc(vv * __builtin_amdgcn_rcpf(1.f + e));
        }
        int chunk = hcolb >> 3;
        *(s16x4*)(hs + xrow * 128 + ((chunk ^ (xrow & 15)) << 3) + (hi & 1) * 4) = o;
      }
    LGKM0;
    BAR;
    #pragma unroll
    for (int s = 0; s < 4; ++s) {
      stage_seq((hc * 8 + 4 + s + 1) & 63, cur ^ 1);
      VMCNT(4);
      BAR;
      const short* Wc = Wb + cur * 8192;
      bf16x8 hf[2], w2f[8];
      #pragma unroll
      for (int m = 0; m < 2; ++m) {
        int xr = wm * 32 + m * 16 + l15;
        hf[m] = *(const bf16x8*)(hs + xr * 128 + (((s * 4 + hi) ^ (xr & 15)) << 3));
      }
      #pragma unroll
      for (int n = 0; n < 8; ++n) {
        int rc = wn * 128 + n * 16 + l15;
        w2f[n] = *(const bf16x8*)(Wc + rc * 32 + ((hi ^ ((rc ^ (rc >> 2)) & 3)) << 3));
      }
      __builtin_amdgcn_s_setprio(1);
      #pragma unroll
      for (int m = 0; m < 2; ++m)
        #pragma unroll
        for (int n = 0; n < 8; ++n)
          oacc[m][n] = mfma16(w2f[n], hf[m], oacc[m][n]);
      __builtin_amdgcn_s_setprio(0);
      LGKM0;
      BAR;
      cur ^= 1;
    }
  }
  #pragma unroll
  for (int m = 0; m < 2; ++m)
    #pragma unroll
    for (int n = 0; n < 8; ++n) {
      size_t row = (size_t)bm0 + wm * 32 + m * 16 + l15;
      int colb = wn * 128 + n * 16 + hi4;
      float4 bbv = *(const float4*)(biasF + 1024 + colb);
      s16x4 hr = *(const s16x4*)(hres + row * 256 + colb);
      float4 ov;
      ov.x = oacc[m][n][0] + bbv.x + bf2f(hr[0]);
      ov.y = oacc[m][n][1] + bbv.y + bf2f(hr[1]);
      ov.z = oacc[m][n][2] + bbv.z + bf2f(hr[2]);
      ov.w = oacc[m][n][3] + bbv.w + bf2f(hr[3]);
      *(float4*)(outp + row * 256 + colb) = ov;
    }
}

// ---------------- host ----------------
extern "C" void kernel_launch(void* const* d_in, const int* in_sizes, int n_in,
                              void* d_out, int out_size, void* d_ws, size_t ws_size,
                              hipStream_t stream) {
  const float* x     = (const float*)d_in[0];
  const float* ln1g  = (const float*)d_in[1];
  const float* ln1b  = (const float*)d_in[2];
  const float* qkvw  = (const float*)d_in[3];
  const float* qkvb  = (const float*)d_in[4];
  const float* projw = (const float*)d_in[5];
  const float* projb = (const float*)d_in[6];
  const float* ln2g  = (const float*)d_in[7];
  const float* ln2b  = (const float*)d_in[8];
  const float* w1    = (const float*)d_in[9];
  const float* b1    = (const float*)d_in[10];
  const float* w2    = (const float*)d_in[11];
  const float* b2    = (const float*)d_in[12];
  float* out = (float*)d_out;
  char* ws = (char*)d_ws;

  static int attr_set = 0;
  if (!attr_set) {
    hipFuncSetAttribute((const void*)k_mlp,
                        hipFuncAttributeMaxDynamicSharedMemorySize, 54272);
    hipFuncSetAttribute((const void*)k_attnproj,
                        hipFuncAttributeMaxDynamicSharedMemorySize, 78848);
    attr_set = 1;
  }

  const size_t MTOT = 131072;
  int nchunk;
  if (ws_size >= 5ull * MTOT * 512 + (2u << 20)) nchunk = 1;
  else if (ws_size >= 5ull * (MTOT / 2) * 512 + (2u << 20)) nchunk = 2;
  else nchunk = 4;
  const size_t M = MTOT / nchunk;
  const int nwin = (int)(M / 64);

  short* qkvS = (short*)ws;                         // 3*M*256 shorts
  short* y2b  = qkvS + 3 * M * 256;                 // M*256
  short* hrb  = y2b + M * 256;                      // M*256
  char*  wreg = ws + 5ull * M * 512;
  short* WqkvT  = (short*)wreg;                      // 393,216 B
  short* WprojT = (short*)(wreg + 393216);           // 131,072 B
  short* W1T    = (short*)(wreg + 524288);           // 524,288 B
  short* W2T    = (short*)(wreg + 1048576);          // 524,288 B
  float* qkvbp  = (float*)(wreg + 1572864);          // 3,072 B

  k_prep<<<3072, 256, 0, stream>>>(qkvw, qkvb, projw, w1, w2,
                                   WqkvT, qkvbp, WprojT, W1T, W2T);

  for (int c = 0; c < nchunk; ++c) {
    k_qkvln<<<nwin, 256, 0, stream>>>(x, ln1g, ln1b, WqkvT, qkvbp, qkvS,
                                      c * nwin, (int)M);
    k_attnproj<<<nwin, 256, 78848, stream>>>(qkvS, WprojT, projb, x, y2b, hrb,
                                             ln2g, ln2b, (int)(c * M), (int)M);
    k_mlp<<<nwin, 256, 54272, stream>>>(y2b, hrb, W1T, b1, W2T, b2,
                                        out + (size_t)c * M * 256);
  }
}

// Round 16
// 504.098 us; speedup vs baseline: 1.1119x; 1.0388x over previous
//
#include <hip/hip_runtime.h>
#include <cstdint>

using bf16x8 = __attribute__((ext_vector_type(8))) __bf16;
using f32x4  = __attribute__((ext_vector_type(4))) float;
using s16x8  = __attribute__((ext_vector_type(8))) short;
using s16x4  = __attribute__((ext_vector_type(4))) short;

#define DI static __device__ __forceinline__

#define SB __builtin_amdgcn_sched_barrier(0)
#define VMCNT(n) do { asm volatile("s_waitcnt vmcnt(" #n ")" ::: "memory"); SB; } while (0)
#define LGKM0    do { asm volatile("s_waitcnt lgkmcnt(0)" ::: "memory"); SB; } while (0)
#define BAR      do { SB; __builtin_amdgcn_s_barrier(); SB; } while (0)

DI short f2bf(float f) {
  unsigned u = __float_as_uint(f);
  u = (u + 0x7fffu + ((u >> 16) & 1u)) >> 16;
  return (short)u;
}
DI short f2bf_trunc(float f) { return (short)(__float_as_uint(f) >> 16); }
DI float bf2f(short s) {
  return __uint_as_float(((unsigned)(unsigned short)s) << 16);
}

DI void gload16(const short* g, short* l) {
  __builtin_amdgcn_global_load_lds((const __attribute__((address_space(1))) unsigned*)g,
                                   (__attribute__((address_space(3))) unsigned*)l, 16, 0, 0);
}

DI f32x4 mfma16(bf16x8 a, bf16x8 b, f32x4 c) {
  return __builtin_amdgcn_mfma_f32_16x16x32_bf16(a, b, c, 0, 0, 0);
}

// Stage a [256 rows x 32 k] bf16 panel (16 KB) into LDS, XOR-swizzled.
template<int CALLS>
DI void stageW(const short* __restrict__ W, int rs, int koff, short* dst, int w, int lane) {
  #pragma unroll
  for (int i = 0; i < CALLS; ++i) {
    int idx = (w * CALLS + i) * 64 + lane;
    int row = idx >> 2, slot = idx & 3;
    gload16(W + (size_t)row * rs + koff + (slot ^ ((row ^ (row >> 2)) & 3)) * 8,
            dst + (w * CALLS + i) * 512);
  }
}

// ---------------- merged weight prep (1 launch) ----------------
__global__ void k_prep(const float* __restrict__ qkvw, const float* __restrict__ qkvb,
                       const float* __restrict__ projw, const float* __restrict__ w1,
                       const float* __restrict__ w2,
                       short* __restrict__ WqkvT, float* __restrict__ qkvbp,
                       short* __restrict__ WprojT, short* __restrict__ W1T,
                       short* __restrict__ W2T) {
  int b = blockIdx.x, tid = threadIdx.x;
  if (b < 768) {
    int idx = b * 256 + tid;
    int jn = idx >> 8, k = idx & 255;
    int q = jn >> 8, rest = jn & 255, h = rest >> 5, d = rest & 31;
    int jo = h * 96 + d * 3 + q;
    WqkvT[idx] = f2bf(qkvw[(size_t)k * 768 + jo]);
    if (k == 0) qkvbp[jn] = qkvb[jo];
  } else if (b < 1024) {
    int idx = (b - 768) * 256 + tid;
    int n = idx >> 8, k = idx & 255;
    WprojT[idx] = f2bf(projw[(size_t)k * 256 + n]);
  } else if (b < 2048) {
    int idx = (b - 1024) * 256 + tid;
    int n = idx >> 8, k = idx & 255;
    W1T[idx] = f2bf(w1[(size_t)k * 1024 + n]);
  } else {
    int idx = (b - 2048) * 256 + tid;
    int n = idx >> 10, k = idx & 1023;
    W2T[idx] = f2bf(w2[(size_t)k * 256 + n]);
  }
}

// ---------------- QKV: fused LN1 + window gather + staged-weight GEMM (R15-exact) --------
__global__ __launch_bounds__(256, 2) void k_qkvln(
    const float* __restrict__ x, const float* __restrict__ g1, const float* __restrict__ b1v,
    const short* __restrict__ WqkvT, const float* __restrict__ qbp,
    short* __restrict__ qkv, int win0, int mtot)
{
  __shared__ __align__(16) short As[64 * 256];      // 32 KB
  __shared__ __align__(16) short Ws[2][256 * 32];   // 2 x 16 KB
  const int tid = threadIdx.x, lane = tid & 63, w = tid >> 6;
  const int l15 = lane & 15, hi = lane >> 4, hi4 = hi * 4;
  const int wg = win0 + blockIdx.x;
  const int bb = wg >> 6, wl = wg & 63, wrr = wl >> 3, wcc = wl & 7;
  stageW<4>(WqkvT, 256, 0, &Ws[0][0], w, lane);     // seq0
  #pragma unroll
  for (int p = 0; p < 4; ++p) {
    int tok = w * 16 + p * 4 + hi;
    int sr = bb * 4096 + ((tok >> 3) * 8 + wrr) * 64 + (tok & 7) * 8 + wcc;
    const float* xr = x + (size_t)sr * 256;
    float4 v[4];
    #pragma unroll
    for (int ii = 0; ii < 4; ++ii) v[ii] = *(const float4*)(xr + l15 * 4 + ii * 64);
    float s = 0.f, q = 0.f;
    #pragma unroll
    for (int ii = 0; ii < 4; ++ii) {
      s += v[ii].x + v[ii].y + v[ii].z + v[ii].w;
      q += v[ii].x * v[ii].x + v[ii].y * v[ii].y + v[ii].z * v[ii].z + v[ii].w * v[ii].w;
    }
    #pragma unroll
    for (int mk = 1; mk < 16; mk <<= 1) { s += __shfl_xor(s, mk); q += __shfl_xor(q, mk); }
    float mean = s * (1.f / 256.f);
    float var  = q * (1.f / 256.f) - mean * mean;
    float rstd = rsqrtf(var + 1e-5f);
    #pragma unroll
    for (int ii = 0; ii < 4; ++ii) {
      float4 gv = *(const float4*)(g1 + l15 * 4 + ii * 64);
      float4 bv = *(const float4*)(b1v + l15 * 4 + ii * 64);
      s16x4 o;
      o[0] = f2bf((v[ii].x - mean) * rstd * gv.x + bv.x);
      o[1] = f2bf((v[ii].y - mean) * rstd * gv.y + bv.y);
      o[2] = f2bf((v[ii].z - mean) * rstd * gv.z + bv.z);
      o[3] = f2bf((v[ii].w - mean) * rstd * gv.w + bv.w);
      int c8 = (l15 >> 1) + ii * 8;
      *(s16x4*)(As + tok * 256 + ((c8 ^ (tok & 7)) << 3) + (l15 & 1) * 4) = o;
    }
  }
  LGKM0;
  BAR;
  bf16x8 af[4][8];
  #pragma unroll
  for (int m = 0; m < 4; ++m) {
    int row = m * 16 + l15;
    #pragma unroll
    for (int s = 0; s < 8; ++s)
      af[m][s] = *(const bf16x8*)(As + row * 256 + (((s * 4 + hi) ^ (row & 7)) << 3));
  }
  int cur = 0;
  for (int p = 0; p < 3; ++p) {
    f32x4 acc[4][4] = {};
    for (int s = 0; s < 8; ++s) {
      int nseq = p * 8 + s + 1; if (nseq >= 24) nseq = 0;
      stageW<4>(WqkvT + (size_t)(nseq >> 3) * 65536, 256, (nseq & 7) * 32,
                &Ws[cur ^ 1][0], w, lane);
      VMCNT(4);
      BAR;
      bf16x8 wf[4];
      #pragma unroll
      for (int n = 0; n < 4; ++n) {
        int rc = w * 64 + n * 16 + l15;
        wf[n] = *(const bf16x8*)(&Ws[cur][0] + rc * 32 + ((hi ^ ((rc ^ (rc >> 2)) & 3)) << 3));
      }
      __builtin_amdgcn_s_setprio(1);
      #pragma unroll
      for (int m = 0; m < 4; ++m)
        #pragma unroll
        for (int n = 0; n < 4; ++n) acc[m][n] = mfma16(wf[n], af[m][s], acc[m][n]);
      __builtin_amdgcn_s_setprio(0);
      LGKM0;
      BAR;
      cur ^= 1;
    }
    const float sc = (p == 0) ? 0.17677669529663687f : 1.0f;
    short* dst = qkv + ((size_t)p * mtot + (size_t)blockIdx.x * 64) * 256;
    #pragma unroll
    for (int n = 0; n < 4; ++n) {
      int colg = w * 64 + n * 16 + hi4;
      float4 bbv = *(const float4*)(qbp + p * 256 + colg);
      #pragma unroll
      for (int m = 0; m < 4; ++m) {
        int row = m * 16 + l15;
        s16x4 o;
        o[0] = f2bf_trunc((acc[m][n][0] + bbv.x) * sc);
        o[1] = f2bf_trunc((acc[m][n][1] + bbv.y) * sc);
        o[2] = f2bf_trunc((acc[m][n][2] + bbv.z) * sc);
        o[3] = f2bf_trunc((acc[m][n][3] + bbv.w) * sc);
        *(s16x4*)(dst + (size_t)row * 256 + colg) = o;
      }
    }
  }
}

// ---------------- fused attention + proj + residual + LN2 ----------------
// One block per window. LDS: VT[256][72] 36864 (->AOs 32K) | Ws 2x16K | Ps[64][72] 9216.
// v2: no-max softmax (|S| bounded, shift-invariant) + next-head K register prefetch.
__global__ __launch_bounds__(256, 2) void k_attnproj(
    const short* __restrict__ qkv, const short* __restrict__ WprojT,
    const float* __restrict__ pb, const float* __restrict__ x,
    short* __restrict__ y2, short* __restrict__ hresb,
    const float* __restrict__ g2, const float* __restrict__ b2,
    int chunk_off, int mtot)
{
  extern __shared__ __align__(16) char dsm[];
  short* VT = (short*)dsm;               // [256 ch][72 tok]; later AOs [64][256] swizzled
  short* Ws = (short*)(dsm + 36864);     // 2 x 8192 shorts
  short* Ps = (short*)(dsm + 69632);     // [64][72]; later redS/redQ
  const int tid = threadIdx.x, lane = tid & 63, w = tid >> 6;
  const int l15 = lane & 15, hi = lane >> 4, hi4 = hi * 4;
  const int win = blockIdx.x, bm0 = win * 64;
  const size_t qbase = (size_t)win * 64 * 256;
  const short* Qg = qkv;
  const short* Kg = qkv + (size_t)mtot * 256;
  const short* Vg = qkv + 2 * (size_t)mtot * 256;

  stageW<4>(WprojT, 256, 0, &Ws[0], w, lane);   // proj panel 0 (lands during attention)

  // V -> VT transpose staging (coalesced global reads, scatter b16 LDS writes)
  {
    int tok = tid >> 2, c4 = (tid & 3) * 8;
    #pragma unroll
    for (int c8 = 0; c8 < 8; ++c8) {
      s16x8 vv = *(const s16x8*)(Vg + qbase + (size_t)tok * 256 + c4 + c8 * 32);
      #pragma unroll
      for (int e = 0; e < 8; ++e) VT[(c4 + c8 * 32 + e) * 72 + tok] = vv[e];
    }
  }
  // Q fragments for this wave's 16 rows, all 8 heads
  bf16x8 aq[8];
  #pragma unroll
  for (int h = 0; h < 8; ++h)
    aq[h] = *(const bf16x8*)(Qg + qbase + (size_t)(w * 16 + l15) * 256 + h * 32 + hi * 8);
  LGKM0;
  BAR;            // VT visible to all waves

  f32x4 zero = {0.f, 0.f, 0.f, 0.f};
  s16x4 ob[8][2];
  // head-0 K fragments preloaded
  bf16x8 bk[4];
  #pragma unroll
  for (int t = 0; t < 4; ++t)
    bk[t] = *(const bf16x8*)(Kg + qbase + (size_t)(t * 16 + l15) * 256 + hi * 8);
  #pragma unroll
  for (int h = 0; h < 8; ++h) {
    f32x4 s[4];
    #pragma unroll
    for (int t = 0; t < 4; ++t) s[t] = mfma16(aq[h], bk[t], zero);
    // prefetch next head's K while softmax + PV run (load-to-use ~ full head body)
    if (h < 7) {
      #pragma unroll
      for (int t = 0; t < 4; ++t)
        bk[t] = *(const bf16x8*)(Kg + qbase + (size_t)(t * 16 + l15) * 256 +
                                 (h + 1) * 32 + hi * 8);
    }
    // softmax over k WITHOUT max-subtraction: |S| bounded (LN inputs, 0.02-scale W,
    // 0.177 Q-scale) far below exp overflow; softmax is shift-invariant.
    float rs[4];
    #pragma unroll
    for (int j = 0; j < 4; ++j) {
      float sum = 0.f;
      #pragma unroll
      for (int t = 0; t < 4; ++t) { float p = __expf(s[t][j]); s[t][j] = p; sum += p; }
      #pragma unroll
      for (int mk = 1; mk < 16; mk <<= 1) sum += __shfl_xor(sum, mk);
      rs[j] = 1.f / sum;
    }
    #pragma unroll
    for (int t = 0; t < 4; ++t)
      #pragma unroll
      for (int j = 0; j < 4; ++j)
        Ps[(w * 16 + hi4 + j) * 72 + t * 16 + l15] = f2bf_trunc(s[t][j] * rs[j]);
    LGKM0;        // same-wave Ps write -> read
    f32x4 o0 = zero, o1 = zero;
    #pragma unroll
    for (int ks = 0; ks < 2; ++ks) {
      bf16x8 ap  = *(const bf16x8*)&Ps[(w * 16 + l15) * 72 + ks * 32 + hi * 8];
      bf16x8 bv0 = *(const bf16x8*)&VT[(h * 32 + l15) * 72 + ks * 32 + hi * 8];
      bf16x8 bv1 = *(const bf16x8*)&VT[(h * 32 + 16 + l15) * 72 + ks * 32 + hi * 8];
      o0 = mfma16(bv0, ap, o0);   // lane -> O[tok=w*16+l15][ch=h*32+hi4+j]
      o1 = mfma16(bv1, ap, o1);   // lane -> O[tok][ch=h*32+16+hi4+j]
    }
    #pragma unroll
    for (int j = 0; j < 4; ++j) { ob[h][0][j] = f2bf_trunc(o0[j]); ob[h][1][j] = f2bf_trunc(o1[j]); }
  }
  BAR;            // all waves done reading VT; safe to overwrite with AOs
  short* AOs = VT;
  {
    int tok = w * 16 + l15;
    #pragma unroll
    for (int h = 0; h < 8; ++h)
      #pragma unroll
      for (int dt = 0; dt < 2; ++dt) {
        int ch = h * 32 + dt * 16 + hi4;
        int chunk = ch >> 3;
        *(s16x4*)(AOs + tok * 256 + ((chunk ^ (tok & 7)) << 3) + (hi4 & 7)) = ob[h][dt];
      }
  }
  LGKM0;
  BAR;            // AOs visible
  // A fragments for proj
  bf16x8 af[4][8];
  #pragma unroll
  for (int m = 0; m < 4; ++m) {
    int row = m * 16 + l15;
    #pragma unroll
    for (int s = 0; s < 8; ++s)
      af[m][s] = *(const bf16x8*)(AOs + row * 256 + (((s * 4 + hi) ^ (row & 7)) << 3));
  }
  // proj GEMM: staged Wproj panels (panel 0 already resident)
  int cur = 0;
  f32x4 acc[4][4] = {};
  for (int s = 0; s < 8; ++s) {
    stageW<4>(WprojT, 256, ((s + 1) & 7) * 32, Ws + (cur ^ 1) * 8192, w, lane);
    VMCNT(4);
    BAR;
    bf16x8 bfr[4];
    #pragma unroll
    for (int n = 0; n < 4; ++n) {
      int rc = w * 64 + n * 16 + l15;
      bfr[n] = *(const bf16x8*)(Ws + cur * 8192 + rc * 32 + ((hi ^ ((rc ^ (rc >> 2)) & 3)) << 3));
    }
    __builtin_amdgcn_s_setprio(1);
    #pragma unroll
    for (int m = 0; m < 4; ++m)
      #pragma unroll
      for (int n = 0; n < 4; ++n) acc[m][n] = mfma16(af[m][s], bfr[n], acc[m][n]);
    __builtin_amdgcn_s_setprio(0);
    LGKM0;
    BAR;
    cur ^= 1;
  }
  // epilogue: + bias + x residual (window->spatial), LN2, write hres + y2
  float* redS = (float*)Ps;
  float* redQ = redS + 256;
  int srow[4][4];
  #pragma unroll
  for (int m = 0; m < 4; ++m)
    #pragma unroll
    for (int j = 0; j < 4; ++j) {
      int wrow = chunk_off + bm0 + m * 16 + hi4 + j;
      int bb = wrow >> 12, rem = wrow & 4095, wn2 = rem >> 6, tok = rem & 63;
      int rsp = (tok >> 3) * 8 + (wn2 >> 3);
      int csp = (tok & 7) * 8 + (wn2 & 7);
      srow[m][j] = bb * 4096 + rsp * 64 + csp;
    }
  float s1[4][4] = {}, s2[4][4] = {};
  #pragma unroll
  for (int m = 0; m < 4; ++m)
    #pragma unroll
    for (int n = 0; n < 4; ++n) {
      int col = w * 64 + n * 16 + l15;
      float bia = pb[col];
      #pragma unroll
      for (int j = 0; j < 4; ++j) {
        float val = acc[m][n][j] + bia + x[(size_t)srow[m][j] * 256 + col];
        acc[m][n][j] = val;
        s1[m][j] += val; s2[m][j] += val * val;
      }
    }
  #pragma unroll
  for (int m = 0; m < 4; ++m)
    #pragma unroll
    for (int j = 0; j < 4; ++j) {
      float a = s1[m][j], bq = s2[m][j];
      #pragma unroll
      for (int mk = 1; mk < 16; mk <<= 1) { a += __shfl_xor(a, mk); bq += __shfl_xor(bq, mk); }
      s1[m][j] = a; s2[m][j] = bq;
    }
  if (l15 == 0) {
    #pragma unroll
    for (int m = 0; m < 4; ++m)
      #pragma unroll
      for (int j = 0; j < 4; ++j) {
        int rl = m * 16 + hi4 + j;
        redS[rl * 4 + w] = s1[m][j];
        redQ[rl * 4 + w] = s2[m][j];
      }
  }
  __syncthreads();
  #pragma unroll
  for (int m = 0; m < 4; ++m)
    #pragma unroll
    for (int j = 0; j < 4; ++j) {
      int rl = m * 16 + hi4 + j;
      float S = redS[rl * 4] + redS[rl * 4 + 1] + redS[rl * 4 + 2] + redS[rl * 4 + 3];
      float Qs = redQ[rl * 4] + redQ[rl * 4 + 1] + redQ[rl * 4 + 2] + redQ[rl * 4 + 3];
      float mean = S * (1.f / 256.f);
      float var  = Qs * (1.f / 256.f) - mean * mean;
      float rstd = rsqrtf(var + 1e-5f);
      int lrow = srow[m][j] - chunk_off;
      #pragma unroll
      for (int n = 0; n < 4; ++n) {
        int col = w * 64 + n * 16 + l15;
        float val = acc[m][n][j];
        hresb[(size_t)lrow * 256 + col] = f2bf(val);
        y2[(size_t)lrow * 256 + col] = f2bf((val - mean) * rstd * g2[col] + b2[col]);
      }
    }
}

// ---------------- fused MLP v11 (R15-exact) ----------------
__global__ __launch_bounds__(256, 2) void k_mlp(
    const short* __restrict__ y2, const short* __restrict__ hres,
    const short* __restrict__ W1T, const float* __restrict__ b1,
    const short* __restrict__ W2T, const float* __restrict__ b2,
    float* __restrict__ outp)
{
  extern __shared__ __align__(16) char dsm[];
  short* hs    = (short*)dsm;
  float* biasF = (float*)(dsm + 16384);
  short* Wb    = (short*)(dsm + 21504);
  const int tid = threadIdx.x, lane = tid & 63, w = tid >> 6;
  const int l15 = lane & 15, hi = lane >> 4, hi4 = hi * 4;
  const int wm = w >> 1, wn = w & 1;
  const int bm0 = blockIdx.x * 64;

  auto stage_seq = [&](int seq, int buf) {
    short* dst = Wb + buf * 8192;
    int hc = (seq >> 3) & 7, t = seq & 7;
    if (t < 4) {
      #pragma unroll
      for (int i = 0; i < 4; ++i) {
        int idx = (w * 4 + i) * 64 + lane;
        int row = idx >> 3, slot = idx & 7;
        gload16(W1T + (size_t)(hc * 128 + row) * 256 + t * 64 + (slot ^ (row & 7)) * 8,
                dst + (w * 4 + i) * 512);
      }
    } else {
      #pragma unroll
      for (int i = 0; i < 4; ++i) {
        int idx = (w * 4 + i) * 64 + lane;
        int row = idx >> 2, slot = idx & 3;
        gload16(W2T + (size_t)row * 1024 + hc * 128 + (t - 4) * 32 +
                    (slot ^ ((row ^ (row >> 2)) & 3)) * 8,
                dst + (w * 4 + i) * 512);
      }
    }
  };

  gload16((const short*)b1 + w * 512 + lane * 8, (short*)biasF + w * 512);
  if (w == 0) gload16((const short*)b2 + lane * 8, (short*)biasF + 2048);
  stage_seq(0, 0);
  bf16x8 af[2][8];
  #pragma unroll
  for (int m = 0; m < 2; ++m) {
    const short* yr = y2 + (size_t)(bm0 + wm * 32 + m * 16 + l15) * 256 + hi * 8;
    #pragma unroll
    for (int kk = 0; kk < 8; ++kk)
      af[m][kk] = *(const bf16x8*)(yr + kk * 32);
  }
  f32x4 oacc[2][8] = {};
  int cur = 0;
  for (int hc = 0; hc < 8; ++hc) {
    f32x4 acc1[2][4] = {};
    #pragma unroll
    for (int s = 0; s < 4; ++s) {
      stage_seq((hc * 8 + s + 1) & 63, cur ^ 1);
      VMCNT(4);
      BAR;
      const short* Wc = Wb + cur * 8192;
      #pragma unroll
      for (int q = 0; q < 2; ++q) {
        int kk = s * 2 + q;
        bf16x8 wf[4];
        #pragma unroll
        for (int n2 = 0; n2 < 4; ++n2) {
          int rc = wn * 64 + n2 * 16 + l15;
          wf[n2] = *(const bf16x8*)(Wc + rc * 64 + (((q * 4 + hi) ^ (rc & 7)) << 3));
        }
        __builtin_amdgcn_s_setprio(1);
        #pragma unroll
        for (int m = 0; m < 2; ++m)
          #pragma unroll
          for (int n2 = 0; n2 < 4; ++n2)
            acc1[m][n2] = mfma16(wf[n2], af[m][kk], acc1[m][n2]);
        __builtin_amdgcn_s_setprio(0);
      }
      LGKM0;
      BAR;
      cur ^= 1;
    }
    #pragma unroll
    for (int m = 0; m < 2; ++m)
      #pragma unroll
      for (int n2 = 0; n2 < 4; ++n2) {
        int xrow = wm * 32 + m * 16 + l15;
        int hcolb = wn * 64 + n2 * 16 + hi4;
        float4 bbv = *(const float4*)(biasF + hc * 128 + hcolb);
        float bj[4] = {bbv.x, bbv.y, bbv.z, bbv.w};
        s16x4 o;
        #pragma unroll
        for (int j = 0; j < 4; ++j) {
          float vv = acc1[m][n2][j] + bj[j];
          float z = vv + 0.044715f * vv * vv * vv;
          float e = __builtin_amdgcn_exp2f(z * -2.3022078900938913f);
          o[j] = f2bf_trunc(vv * __builtin_amdgcn_rcpf(1.f + e));
        }
        int chunk = hcolb >> 3;
        *(s16x4*)(hs + xrow * 128 + ((chunk ^ (xrow & 15)) << 3) + (hi & 1) * 4) = o;
      }
    LGKM0;
    BAR;
    #pragma unroll
    for (int s = 0; s < 4; ++s) {
      stage_seq((hc * 8 + 4 + s + 1) & 63, cur ^ 1);
      VMCNT(4);
      BAR;
      const short* Wc = Wb + cur * 8192;
      bf16x8 hf[2], w2f[8];
      #pragma unroll
      for (int m = 0; m < 2; ++m) {
        int xr = wm * 32 + m * 16 + l15;
        hf[m] = *(const bf16x8*)(hs + xr * 128 + (((s * 4 + hi) ^ (xr & 15)) << 3));
      }
      #pragma unroll
      for (int n = 0; n < 8; ++n) {
        int rc = wn * 128 + n * 16 + l15;
        w2f[n] = *(const bf16x8*)(Wc + rc * 32 + ((hi ^ ((rc ^ (rc >> 2)) & 3)) << 3));
      }
      __builtin_amdgcn_s_setprio(1);
      #pragma unroll
      for (int m = 0; m < 2; ++m)
        #pragma unroll
        for (int n = 0; n < 8; ++n)
          oacc[m][n] = mfma16(w2f[n], hf[m], oacc[m][n]);
      __builtin_amdgcn_s_setprio(0);
      LGKM0;
      BAR;
      cur ^= 1;
    }
  }
  #pragma unroll
  for (int m = 0; m < 2; ++m)
    #pragma unroll
    for (int n = 0; n < 8; ++n) {
      size_t row = (size_t)bm0 + wm * 32 + m * 16 + l15;
      int colb = wn * 128 + n * 16 + hi4;
      float4 bbv = *(const float4*)(biasF + 1024 + colb);
      s16x4 hr = *(const s16x4*)(hres + row * 256 + colb);
      float4 ov;
      ov.x = oacc[m][n][0] + bbv.x + bf2f(hr[0]);
      ov.y = oacc[m][n][1] + bbv.y + bf2f(hr[1]);
      ov.z = oacc[m][n][2] + bbv.z + bf2f(hr[2]);
      ov.w = oacc[m][n][3] + bbv.w + bf2f(hr[3]);
      *(float4*)(outp + row * 256 + colb) = ov;
    }
}

// ---------------- host ----------------
extern "C" void kernel_launch(void* const* d_in, const int* in_sizes, int n_in,
                              void* d_out, int out_size, void* d_ws, size_t ws_size,
                              hipStream_t stream) {
  const float* x     = (const float*)d_in[0];
  const float* ln1g  = (const float*)d_in[1];
  const float* ln1b  = (const float*)d_in[2];
  const float* qkvw  = (const float*)d_in[3];
  const float* qkvb  = (const float*)d_in[4];
  const float* projw = (const float*)d_in[5];
  const float* projb = (const float*)d_in[6];
  const float* ln2g  = (const float*)d_in[7];
  const float* ln2b  = (const float*)d_in[8];
  const float* w1    = (const float*)d_in[9];
  const float* b1    = (const float*)d_in[10];
  const float* w2    = (const float*)d_in[11];
  const float* b2    = (const float*)d_in[12];
  float* out = (float*)d_out;
  char* ws = (char*)d_ws;

  static int attr_set = 0;
  if (!attr_set) {
    hipFuncSetAttribute((const void*)k_mlp,
                        hipFuncAttributeMaxDynamicSharedMemorySize, 54272);
    hipFuncSetAttribute((const void*)k_attnproj,
                        hipFuncAttributeMaxDynamicSharedMemorySize, 78848);
    attr_set = 1;
  }

  const size_t MTOT = 131072;
  int nchunk;
  if (ws_size >= 5ull * MTOT * 512 + (2u << 20)) nchunk = 1;
  else if (ws_size >= 5ull * (MTOT / 2) * 512 + (2u << 20)) nchunk = 2;
  else nchunk = 4;
  const size_t M = MTOT / nchunk;
  const int nwin = (int)(M / 64);

  short* qkvS = (short*)ws;                         // 3*M*256 shorts
  short* y2b  = qkvS + 3 * M * 256;                 // M*256
  short* hrb  = y2b + M * 256;                      // M*256
  char*  wreg = ws + 5ull * M * 512;
  short* WqkvT  = (short*)wreg;                      // 393,216 B
  short* WprojT = (short*)(wreg + 393216);           // 131,072 B
  short* W1T    = (short*)(wreg + 524288);           // 524,288 B
  short* W2T    = (short*)(wreg + 1048576);          // 524,288 B
  float* qkvbp  = (float*)(wreg + 1572864);          // 3,072 B

  k_prep<<<3072, 256, 0, stream>>>(qkvw, qkvb, projw, w1, w2,
                                   WqkvT, qkvbp, WprojT, W1T, W2T);

  for (int c = 0; c < nchunk; ++c) {
    k_qkvln<<<nwin, 256, 0, stream>>>(x, ln1g, ln1b, WqkvT, qkvbp, qkvS,
                                      c * nwin, (int)M);
    k_attnproj<<<nwin, 256, 78848, stream>>>(qkvS, WprojT, projb, x, y2b, hrb,
                                             ln2g, ln2b, (int)(c * M), (int)M);
    k_mlp<<<nwin, 256, 54272, stream>>>(y2b, hrb, W1T, b1, W2T, b2,
                                        out + (size_t)c * M * 256);
  }
}